// Round 8
// baseline (600.978 us; speedup 1.0000x reference)
//
#include <hip/hip_runtime.h>

#define N 4096
#define IN_F 256
#define SLOPE 0.01f
#define CAP 512      // LDS neighbor-list capacity per row (mean ~41, 70+ sigma safe)
#define NBR_CAP 128  // persisted neighbor list capacity (worst row ~80)

typedef float f4 __attribute__((ext_vector_type(4)));

__device__ __forceinline__ float leaky(float v) { return v >= 0.f ? v : SLOPE * v; }

// ---------------------------------------------------------------------------
// Wh[r] = x @ W_r  (x: [N,256], W: [256,64]) + fused s_src/s_dst epilogue.
// grid (N/64, 3), block 256
// ---------------------------------------------------------------------------
__global__ __launch_bounds__(256) void k_wh(const float* __restrict__ x,
                                            const float* __restrict__ W1,
                                            const float* __restrict__ W2,
                                            const float* __restrict__ W3,
                                            const float* __restrict__ a1,
                                            const float* __restrict__ a2,
                                            const float* __restrict__ a3,
                                            float* __restrict__ Wh,
                                            float* __restrict__ ssrc,
                                            float* __restrict__ sdst) {
  const int r = blockIdx.y;
  const float* W = (r == 0) ? W1 : (r == 1 ? W2 : W3);
  const float* aW = (r == 0) ? a1 : (r == 1 ? a2 : a3);
  const int row0 = blockIdx.x * 64;
  __shared__ float xs[64][32];
  __shared__ float wsh[32][64];
  const int tid = threadIdx.x;
  const int f = tid & 63;
  const int rg = tid >> 6;  // 0..3
  float acc[16];
#pragma unroll
  for (int t = 0; t < 16; ++t) acc[t] = 0.f;

  for (int kb = 0; kb < IN_F; kb += 32) {
#pragma unroll
    for (int t = 0; t < 8; ++t) {  // 64x32 x-tile
      int idx = tid + t * 256;
      int rr = idx >> 5, cc = idx & 31;
      xs[rr][cc] = x[(size_t)(row0 + rr) * IN_F + kb + cc];
    }
#pragma unroll
    for (int t = 0; t < 8; ++t) {  // 32x64 W-tile
      int idx = tid + t * 256;
      int rr = idx >> 6, cc = idx & 63;
      wsh[rr][cc] = W[(size_t)(kb + rr) * 64 + cc];
    }
    __syncthreads();
#pragma unroll
    for (int kk = 0; kk < 32; ++kk) {
      float wv = wsh[kk][f];
#pragma unroll
      for (int t = 0; t < 16; ++t) acc[t] += xs[rg * 16 + t][kk] * wv;
    }
    __syncthreads();
  }
  float* outp = Wh + ((size_t)r * N + row0 + rg * 16) * 64 + f;
#pragma unroll
  for (int t = 0; t < 16; ++t) outp[(size_t)t * 64] = acc[t];

  // fused scores epilogue: s_src = Wh·a[:64], s_dst = Wh·a[64:]
  const float asrc = aW[f];
  const float adst = aW[64 + f];
#pragma unroll
  for (int t = 0; t < 16; ++t) {
    float p = acc[t] * asrc;
    float q = acc[t] * adst;
#pragma unroll
    for (int off = 32; off; off >>= 1) {
      p += __shfl_down(p, off);
      q += __shfl_down(q, off);
    }
    if (f == 0) {
      const int row = row0 + rg * 16 + t;
      ssrc[r * N + row] = p;
      sdst[r * N + row] = q;
    }
  }
}

// ---------------------------------------------------------------------------
// Fused: mask -> exact softmax -> attn@Wh for one (relation, row).
// Also persists neighbor list + 1/deg for the GNN relation.
// grid (N, 3), block 256. Streams the 16KB adj row exactly once.
// ---------------------------------------------------------------------------
__global__ __launch_bounds__(256) void k_attn(const float* __restrict__ adj,
                                              const float* __restrict__ Wh,
                                              const float* __restrict__ ssrc,
                                              const float* __restrict__ sdst,
                                              const int* __restrict__ relp,
                                              float* __restrict__ hout,
                                              int* __restrict__ nbr,
                                              int* __restrict__ nbrc,
                                              float* __restrict__ dinv) {
  const int r = blockIdx.y;
  const int i = blockIdx.x;
  const int tid = threadIdx.x;

  __shared__ int s_idx[CAP];
  __shared__ float s_p[CAP];
  __shared__ int s_cnt;
  __shared__ float s_max[4];
  __shared__ float s_sum[4];
  __shared__ float s_acc[4][64];

  if (tid == 0) s_cnt = 0;
  __syncthreads();

  const f4* arow4 = (const f4*)(adj + ((size_t)r * N + i) * N);
  const float* sd = sdst + r * N;
  float mx = -1e30f;
#pragma unroll
  for (int t = 0; t < 4; ++t) {
    const int j4 = tid + t * 256;
    const f4 v = arow4[j4];
    const int jb = j4 * 4;
    if (v.x != 0.f) { int p = atomicAdd(&s_cnt, 1); if (p < CAP) s_idx[p] = jb;     mx = fmaxf(mx, sd[jb]); }
    if (v.y != 0.f) { int p = atomicAdd(&s_cnt, 1); if (p < CAP) s_idx[p] = jb + 1; mx = fmaxf(mx, sd[jb + 1]); }
    if (v.z != 0.f) { int p = atomicAdd(&s_cnt, 1); if (p < CAP) s_idx[p] = jb + 2; mx = fmaxf(mx, sd[jb + 2]); }
    if (v.w != 0.f) { int p = atomicAdd(&s_cnt, 1); if (p < CAP) s_idx[p] = jb + 3; mx = fmaxf(mx, sd[jb + 3]); }
  }
  // block-reduce max of s_dst over neighbors
#pragma unroll
  for (int off = 32; off; off >>= 1) mx = fmaxf(mx, __shfl_down(mx, off));
  if ((tid & 63) == 0) s_max[tid >> 6] = mx;
  __syncthreads();

  const int Ktrue = s_cnt;
  const int K = (Ktrue < CAP) ? Ktrue : CAP;
  const float mdst = fmaxf(fmaxf(s_max[0], s_max[1]), fmaxf(s_max[2], s_max[3]));
  const float si = ssrc[r * N + i];
  const float M = leaky(si + mdst);  // exact row max (leaky is monotone increasing)

  // p_k = exp(score_k - M), denom = sum
  float lsum = 0.f;
  for (int k = tid; k < K; k += 256) {
    const float sc = leaky(si + sd[s_idx[k]]);
    const float p = expf(sc - M);
    s_p[k] = p;
    lsum += p;
  }
#pragma unroll
  for (int off = 32; off; off >>= 1) lsum += __shfl_down(lsum, off);
  if ((tid & 63) == 0) s_sum[tid >> 6] = lsum;
  __syncthreads();
  const float inv = 1.f / (s_sum[0] + s_sum[1] + s_sum[2] + s_sum[3]);

  // h[i] = (sum_k p_k * Wh[j_k]) * inv   — 4 waves split neighbors, 64 dims/lane
  const int f = tid & 63;
  const int g = tid >> 6;
  const float* WhR = Wh + (size_t)r * N * 64;
  float acc = 0.f;
  for (int k = g; k < K; k += 4) acc += s_p[k] * WhR[(size_t)s_idx[k] * 64 + f];
  s_acc[g][f] = acc;
  __syncthreads();
  if (g == 0) {
    float tot = (s_acc[0][f] + s_acc[1][f]) + (s_acc[2][f] + s_acc[3][f]);
    hout[((size_t)r * N + i) * 64 + f] = tot * inv;
  }

  // persist sparse structure for the GNN layers (only for the chosen relation)
  if (r == relp[0]) {
    const int Kp = (K < NBR_CAP) ? K : NBR_CAP;
    if (tid == 0) {
      nbrc[i] = Kp;
      dinv[i] = 1.f / (float)Ktrue;  // deg = row sum = nnz count (values are 0/1)
    }
    for (int k = tid; k < Kp; k += 256) nbr[i * NBR_CAP + k] = s_idx[k];
  }
}

// ---------------------------------------------------------------------------
// hp = sigmoid((h1+h2+h3)/3); support0 = hp @ Wg0 ([64,64])
// grid N/64, block 256
// ---------------------------------------------------------------------------
__global__ __launch_bounds__(256) void k_support0(const float* __restrict__ h,
                                                  const float* __restrict__ Wg0,
                                                  float* __restrict__ sup0) {
  __shared__ float hp[64][64];
  __shared__ float wg[64][64];
  const int tid = threadIdx.x;
  const int row0 = blockIdx.x * 64;
  const float* h1 = h;
  const float* h2 = h + (size_t)N * 64;
  const float* h3 = h + (size_t)2 * N * 64;
#pragma unroll
  for (int t = 0; t < 16; ++t) {
    int idx = tid + t * 256;
    wg[idx >> 6][idx & 63] = Wg0[idx];
    size_t gi = (size_t)row0 * 64 + idx;
    float v = (h1[gi] + h2[gi] + h3[gi]) * (1.f / 3.f);
    hp[idx >> 6][idx & 63] = 1.f / (1.f + expf(-v));
  }
  __syncthreads();
  const int f = tid & 63;
  const int g = tid >> 6;
  for (int n = g; n < 64; n += 4) {
    float acc = 0.f;
#pragma unroll
    for (int k = 0; k < 64; ++k) acc += hp[n][k] * wg[k][f];
    sup0[((size_t)row0 + n) * 64 + f] = acc;
  }
}

// ---------------------------------------------------------------------------
// Fused GNN layer 0 epilogue + layer-1 GEMMs, 4 rows per block:
//   out0[i]  = leaky(dinv[i] * sum_{j in nbr(i)} sup0[j] + bg0)   (kept in LDS)
//   s1[i]    = out0[i] @ Wg1            (Wg1: [64,32])
//   resid[i] = out0[i] @ Wr^T + br      (Wr: [32,64] torch layout)
// grid N/4, block 256
// ---------------------------------------------------------------------------
__global__ __launch_bounds__(256) void k_agg0_gemm1(const float* __restrict__ sup,
                                                    const int* __restrict__ nbr,
                                                    const int* __restrict__ nbrc,
                                                    const float* __restrict__ dinv,
                                                    const float* __restrict__ bg0,
                                                    const float* __restrict__ Wg1,
                                                    const float* __restrict__ Wr,
                                                    const float* __restrict__ br,
                                                    float* __restrict__ s1,
                                                    float* __restrict__ resid) {
  __shared__ float wg[64][32];
  __shared__ float wrT[64][33];  // padded; wrT[k][ff] = Wr[ff][k]
  __shared__ float row_s[4][64];
  const int tid = threadIdx.x;
#pragma unroll
  for (int t = 0; t < 8; ++t) {
    int idx = tid + t * 256;
    wg[idx >> 5][idx & 31] = Wg1[idx];
    wrT[idx & 63][idx >> 6] = Wr[idx];
  }
  const int f = tid & 63;
  const int g = tid >> 6;
  const int i = blockIdx.x * 4 + g;

  // --- agg0: out0 row into LDS ---
  const int K = nbrc[i];
  const int* nb = nbr + (size_t)i * NBR_CAP;
  float acc = 0.f;
  for (int k = 0; k < K; ++k) acc += sup[(size_t)nb[k] * 64 + f];
  row_s[g][f] = leaky(acc * dinv[i] + bg0[f]);
  __syncthreads();

  // --- layer-1 GEMMs from LDS ---
  const float* row = row_s[g];
  if (f < 32) {
    float a2 = 0.f;
#pragma unroll
    for (int k = 0; k < 64; ++k) a2 += row[k] * wg[k][f];
    s1[(size_t)i * 32 + f] = a2;
  } else {
    const int ff = f - 32;
    float a2 = br[ff];
#pragma unroll
    for (int k = 0; k < 64; ++k) a2 += row[k] * wrT[k][ff];
    resid[(size_t)i * 32 + ff] = a2;
  }
}

// ---------------------------------------------------------------------------
// out[i] = leaky(dinv[i] * sum_j s1[j] + bg1) + resid[i]   grid N/8, block 256
// ---------------------------------------------------------------------------
__global__ __launch_bounds__(256) void k_agg1(const float* __restrict__ s1,
                                              const float* __restrict__ resid,
                                              const int* __restrict__ nbr,
                                              const int* __restrict__ nbrc,
                                              const float* __restrict__ dinv,
                                              const float* __restrict__ bias,
                                              float* __restrict__ out) {
  const int tid = threadIdx.x;
  const int f = tid & 31;
  const int g = tid >> 5;
  const int i = blockIdx.x * 8 + g;
  const int K = nbrc[i];
  const int* nb = nbr + (size_t)i * NBR_CAP;
  float acc = 0.f;
  for (int k = 0; k < K; ++k) acc += s1[(size_t)nb[k] * 32 + f];
  out[(size_t)i * 32 + f] = leaky(acc * dinv[i] + bias[f]) + resid[(size_t)i * 32 + f];
}

// ---------------------------------------------------------------------------
// ATTRIBUTION EXPERIMENT: launch the identical pipeline TWICE.
// All kernels are idempotent (every output buffer fully rewritten with the
// same values), so correctness is unchanged. dur(this) - dur(R5) = true cost
// of one pipeline pass (L3-warm); the remainder is fixed harness overhead.
// ---------------------------------------------------------------------------
extern "C" void kernel_launch(void* const* d_in, const int* in_sizes, int n_in,
                              void* d_out, int out_size, void* d_ws, size_t ws_size,
                              hipStream_t stream) {
  const float* x   = (const float*)d_in[0];
  const float* adj = (const float*)d_in[1];
  const float* W1  = (const float*)d_in[2];
  const float* a1  = (const float*)d_in[3];
  const float* W2  = (const float*)d_in[4];
  const float* a2  = (const float*)d_in[5];
  const float* W3  = (const float*)d_in[6];
  const float* a3  = (const float*)d_in[7];
  const float* Wg0 = (const float*)d_in[8];
  const float* bg0 = (const float*)d_in[9];
  const float* Wg1 = (const float*)d_in[10];
  const float* bg1 = (const float*)d_in[11];
  const float* Wr  = (const float*)d_in[12];
  const float* br  = (const float*)d_in[13];
  const int*   rel = (const int*)d_in[14];
  float* out = (float*)d_out;

  char* ws = (char*)d_ws;
  float* Wh    = (float*)(ws + 0);         // 3*N*64 f32 = 3 MB
  float* h     = (float*)(ws + 3145728);   // 3*N*64
  float* ssrc  = (float*)(ws + 6291456);   // 3*N
  float* sdst  = (float*)(ws + 6340608);   // 3*N
  int*   nbr   = (int*)  (ws + 6389760);   // N*128 int
  int*   nbrc  = (int*)  (ws + 8486912);   // N int
  float* dinv  = (float*)(ws + 8503296);   // N
  float* sup0  = (float*)(ws + 8519680);   // N*64
  float* s1    = (float*)(ws + 9568256);   // N*32
  float* resid = (float*)(ws + 10092544);  // N*32  (ends 10616832 bytes)

  for (int rep = 0; rep < 2; ++rep) {
    k_wh<<<dim3(N / 64, 3), 256, 0, stream>>>(x, W1, W2, W3, a1, a2, a3, Wh, ssrc, sdst);
    k_attn<<<dim3(N, 3), 256, 0, stream>>>(adj, Wh, ssrc, sdst, rel, h, nbr, nbrc, dinv);
    k_support0<<<N / 64, 256, 0, stream>>>(h, Wg0, sup0);
    k_agg0_gemm1<<<N / 4, 256, 0, stream>>>(sup0, nbr, nbrc, dinv, bg0, Wg1, Wr, br, s1, resid);
    k_agg1<<<N / 8, 256, 0, stream>>>(s1, resid, nbr, nbrc, dinv, bg1, out);
  }
}

// Round 9
// 406.053 us; speedup vs baseline: 1.4800x; 1.4800x over previous
//
#include <hip/hip_runtime.h>

#define N 4096
#define IN_F 256
#define SLOPE 0.01f
#define CAP 512      // LDS neighbor-list capacity per row (mean ~41, never hit at 1%)
#define NBR_CAP 128  // persisted neighbor list capacity (worst row ~80)

typedef float f4 __attribute__((ext_vector_type(4)));

__device__ __forceinline__ float leaky(float v) { return v >= 0.f ? v : SLOPE * v; }

// ---------------------------------------------------------------------------
// Wh[r] = x @ W_r  (x: [N,256], W: [256,64]) + fused s_src/s_dst epilogue.
// grid (N/64, 3), block 256
// ---------------------------------------------------------------------------
__global__ __launch_bounds__(256) void k_wh(const float* __restrict__ x,
                                            const float* __restrict__ W1,
                                            const float* __restrict__ W2,
                                            const float* __restrict__ W3,
                                            const float* __restrict__ a1,
                                            const float* __restrict__ a2,
                                            const float* __restrict__ a3,
                                            float* __restrict__ Wh,
                                            float* __restrict__ ssrc,
                                            float* __restrict__ sdst) {
  const int r = blockIdx.y;
  const float* W = (r == 0) ? W1 : (r == 1 ? W2 : W3);
  const float* aW = (r == 0) ? a1 : (r == 1 ? a2 : a3);
  const int row0 = blockIdx.x * 64;
  __shared__ float xs[64][32];
  __shared__ float wsh[32][64];
  const int tid = threadIdx.x;
  const int f = tid & 63;
  const int rg = tid >> 6;  // 0..3
  float acc[16];
#pragma unroll
  for (int t = 0; t < 16; ++t) acc[t] = 0.f;

  for (int kb = 0; kb < IN_F; kb += 32) {
#pragma unroll
    for (int t = 0; t < 8; ++t) {  // 64x32 x-tile
      int idx = tid + t * 256;
      int rr = idx >> 5, cc = idx & 31;
      xs[rr][cc] = x[(size_t)(row0 + rr) * IN_F + kb + cc];
    }
#pragma unroll
    for (int t = 0; t < 8; ++t) {  // 32x64 W-tile
      int idx = tid + t * 256;
      int rr = idx >> 6, cc = idx & 63;
      wsh[rr][cc] = W[(size_t)(kb + rr) * 64 + cc];
    }
    __syncthreads();
#pragma unroll
    for (int kk = 0; kk < 32; ++kk) {
      float wv = wsh[kk][f];
#pragma unroll
      for (int t = 0; t < 16; ++t) acc[t] += xs[rg * 16 + t][kk] * wv;
    }
    __syncthreads();
  }
  float* outp = Wh + ((size_t)r * N + row0 + rg * 16) * 64 + f;
#pragma unroll
  for (int t = 0; t < 16; ++t) outp[(size_t)t * 64] = acc[t];

  // fused scores epilogue: s_src = Wh·a[:64], s_dst = Wh·a[64:]
  const float asrc = aW[f];
  const float adst = aW[64 + f];
#pragma unroll
  for (int t = 0; t < 16; ++t) {
    float p = acc[t] * asrc;
    float q = acc[t] * adst;
#pragma unroll
    for (int off = 32; off; off >>= 1) {
      p += __shfl_down(p, off);
      q += __shfl_down(q, off);
    }
    if (f == 0) {
      const int row = row0 + rg * 16 + t;
      ssrc[r * N + row] = p;
      sdst[r * N + row] = q;
    }
  }
}

// ---------------------------------------------------------------------------
// Wave-per-row fused attention: ballot-compact scan -> exact softmax -> PV.
// No atomics, no __syncthreads; all cross-lane via ballot/shfl.
// grid (N/4, 3), block 256 (4 waves = 4 rows per block).
// ---------------------------------------------------------------------------
__global__ __launch_bounds__(256) void k_attn(const float* __restrict__ adj,
                                              const float* __restrict__ Wh,
                                              const float* __restrict__ ssrc,
                                              const float* __restrict__ sdst,
                                              const int* __restrict__ relp,
                                              float* __restrict__ hout,
                                              int* __restrict__ nbr,
                                              int* __restrict__ nbrc,
                                              float* __restrict__ dinv) {
  const int r = blockIdx.y;
  const int wave = threadIdx.x >> 6;
  const int lane = threadIdx.x & 63;
  const int i = blockIdx.x * 4 + wave;

  __shared__ int s_idx_all[4][CAP];
  __shared__ float s_p_all[4][CAP];
  int* s_idx = s_idx_all[wave];
  float* s_p = s_p_all[wave];

  const f4* arow4 = (const f4*)(adj + ((size_t)r * N + i) * N);
  const float* sd = sdst + r * N;

  // --- scan: load 16 f4/lane (stride-64 => 1KB/instr coalesced), then
  //     ballot-compact nonzero indices into s_idx. base is wave-uniform.
  f4 v[16];
#pragma unroll
  for (int t = 0; t < 16; ++t) v[t] = arow4[t * 64 + lane];

  const unsigned long long lmask = (1ULL << lane) - 1ULL;
  int base = 0;
#pragma unroll
  for (int t = 0; t < 16; ++t) {
#pragma unroll
    for (int c = 0; c < 4; ++c) {
      const bool nz = (v[t][c] != 0.f);
      const unsigned long long m = __ballot(nz);
      if (nz) {
        const int pos = base + __popcll(m & lmask);
        if (pos < CAP) s_idx[pos] = (t * 64 + lane) * 4 + c;
      }
      base += __popcll(m);
    }
  }
  const int Ktrue = base;
  const int K = (Ktrue < CAP) ? Ktrue : CAP;

  // --- exact row max: M = leaky(si + max_nbr sd) (leaky monotone) ---
  const float si = ssrc[r * N + i];
  float sdv = 0.f;
  float mx = -1e30f;
  if (lane < K) {
    sdv = sd[s_idx[lane]];
    mx = sdv;
  }
  for (int k = 64 + lane; k < K; k += 64) mx = fmaxf(mx, sd[s_idx[k]]);  // rare tail
#pragma unroll
  for (int off = 1; off < 64; off <<= 1) mx = fmaxf(mx, __shfl_xor(mx, off));
  const float M = leaky(si + mx);

  // --- p_k = exp(score - M); denom via butterfly (all lanes get it) ---
  float lsum = 0.f;
  if (lane < K) {
    const float p = __expf(leaky(si + sdv) - M);
    s_p[lane] = p;
    lsum = p;
  }
  for (int k = 64 + lane; k < K; k += 64) {  // rare tail
    const float p = __expf(leaky(si + sd[s_idx[k]]) - M);
    s_p[k] = p;
    lsum += p;
  }
#pragma unroll
  for (int off = 1; off < 64; off <<= 1) lsum += __shfl_xor(lsum, off);
  const float inv = 1.f / lsum;

  // --- PV: h[i][lane] = sum_k p_k * Wh[j_k][lane], 4-way unrolled MLP ---
  const float* WhR = Wh + (size_t)r * N * 64;
  float acc = 0.f;
  int k = 0;
  for (; k + 4 <= K; k += 4) {
    const int i0 = s_idx[k], i1 = s_idx[k + 1], i2 = s_idx[k + 2], i3 = s_idx[k + 3];
    const float w0 = s_p[k], w1 = s_p[k + 1], w2 = s_p[k + 2], w3 = s_p[k + 3];
    acc += w0 * WhR[(size_t)i0 * 64 + lane];
    acc += w1 * WhR[(size_t)i1 * 64 + lane];
    acc += w2 * WhR[(size_t)i2 * 64 + lane];
    acc += w3 * WhR[(size_t)i3 * 64 + lane];
  }
  for (; k < K; ++k) acc += s_p[k] * WhR[(size_t)s_idx[k] * 64 + lane];
  hout[((size_t)r * N + i) * 64 + lane] = acc * inv;

  // --- persist sparse structure for the GNN relation ---
  if (r == relp[0]) {
    const int Kp = (K < NBR_CAP) ? K : NBR_CAP;
    if (lane == 0) {
      nbrc[i] = Kp;
      dinv[i] = 1.f / (float)Ktrue;  // deg = nnz count (0/1 values)
    }
    for (int kk = lane; kk < Kp; kk += 64) nbr[i * NBR_CAP + kk] = s_idx[kk];
  }
}

// ---------------------------------------------------------------------------
// hp = sigmoid((h1+h2+h3)/3); support0 = hp @ Wg0 ([64,64])
// grid N/64, block 256
// ---------------------------------------------------------------------------
__global__ __launch_bounds__(256) void k_support0(const float* __restrict__ h,
                                                  const float* __restrict__ Wg0,
                                                  float* __restrict__ sup0) {
  __shared__ float hp[64][64];
  __shared__ float wg[64][64];
  const int tid = threadIdx.x;
  const int row0 = blockIdx.x * 64;
  const float* h1 = h;
  const float* h2 = h + (size_t)N * 64;
  const float* h3 = h + (size_t)2 * N * 64;
#pragma unroll
  for (int t = 0; t < 16; ++t) {
    int idx = tid + t * 256;
    wg[idx >> 6][idx & 63] = Wg0[idx];
    size_t gi = (size_t)row0 * 64 + idx;
    float v = (h1[gi] + h2[gi] + h3[gi]) * (1.f / 3.f);
    hp[idx >> 6][idx & 63] = 1.f / (1.f + __expf(-v));
  }
  __syncthreads();
  const int f = tid & 63;
  const int g = tid >> 6;
  for (int n = g; n < 64; n += 4) {
    float acc = 0.f;
#pragma unroll
    for (int k = 0; k < 64; ++k) acc += hp[n][k] * wg[k][f];
    sup0[((size_t)row0 + n) * 64 + f] = acc;
  }
}

// ---------------------------------------------------------------------------
// Fused GNN layer 0 epilogue + layer-1 GEMMs, 4 rows per block:
//   out0[i]  = leaky(dinv[i] * sum_{j in nbr(i)} sup0[j] + bg0)   (kept in LDS)
//   s1[i]    = out0[i] @ Wg1            (Wg1: [64,32])
//   resid[i] = out0[i] @ Wr^T + br      (Wr: [32,64] torch layout)
// grid N/4, block 256
// ---------------------------------------------------------------------------
__global__ __launch_bounds__(256) void k_agg0_gemm1(const float* __restrict__ sup,
                                                    const int* __restrict__ nbr,
                                                    const int* __restrict__ nbrc,
                                                    const float* __restrict__ dinv,
                                                    const float* __restrict__ bg0,
                                                    const float* __restrict__ Wg1,
                                                    const float* __restrict__ Wr,
                                                    const float* __restrict__ br,
                                                    float* __restrict__ s1,
                                                    float* __restrict__ resid) {
  __shared__ float wg[64][32];
  __shared__ float wrT[64][33];  // padded; wrT[k][ff] = Wr[ff][k]
  __shared__ float row_s[4][64];
  const int tid = threadIdx.x;
#pragma unroll
  for (int t = 0; t < 8; ++t) {
    int idx = tid + t * 256;
    wg[idx >> 5][idx & 31] = Wg1[idx];
    wrT[idx & 63][idx >> 6] = Wr[idx];
  }
  const int f = tid & 63;
  const int g = tid >> 6;
  const int i = blockIdx.x * 4 + g;

  // --- agg0: out0 row into LDS ---
  const int K = nbrc[i];
  const int* nb = nbr + (size_t)i * NBR_CAP;
  float acc = 0.f;
  for (int k = 0; k < K; ++k) acc += sup[(size_t)nb[k] * 64 + f];
  row_s[g][f] = leaky(acc * dinv[i] + bg0[f]);
  __syncthreads();

  // --- layer-1 GEMMs from LDS ---
  const float* row = row_s[g];
  if (f < 32) {
    float a2 = 0.f;
#pragma unroll
    for (int k = 0; k < 64; ++k) a2 += row[k] * wg[k][f];
    s1[(size_t)i * 32 + f] = a2;
  } else {
    const int ff = f - 32;
    float a2 = br[ff];
#pragma unroll
    for (int k = 0; k < 64; ++k) a2 += row[k] * wrT[k][ff];
    resid[(size_t)i * 32 + ff] = a2;
  }
}

// ---------------------------------------------------------------------------
// out[i] = leaky(dinv[i] * sum_j s1[j] + bg1) + resid[i]   grid N/8, block 256
// ---------------------------------------------------------------------------
__global__ __launch_bounds__(256) void k_agg1(const float* __restrict__ s1,
                                              const float* __restrict__ resid,
                                              const int* __restrict__ nbr,
                                              const int* __restrict__ nbrc,
                                              const float* __restrict__ dinv,
                                              const float* __restrict__ bias,
                                              float* __restrict__ out) {
  const int tid = threadIdx.x;
  const int f = tid & 31;
  const int g = tid >> 5;
  const int i = blockIdx.x * 8 + g;
  const int K = nbrc[i];
  const int* nb = nbr + (size_t)i * NBR_CAP;
  float acc = 0.f;
  for (int k = 0; k < K; ++k) acc += s1[(size_t)nb[k] * 32 + f];
  out[(size_t)i * 32 + f] = leaky(acc * dinv[i] + bias[f]) + resid[(size_t)i * 32 + f];
}

// ---------------------------------------------------------------------------
extern "C" void kernel_launch(void* const* d_in, const int* in_sizes, int n_in,
                              void* d_out, int out_size, void* d_ws, size_t ws_size,
                              hipStream_t stream) {
  const float* x   = (const float*)d_in[0];
  const float* adj = (const float*)d_in[1];
  const float* W1  = (const float*)d_in[2];
  const float* a1  = (const float*)d_in[3];
  const float* W2  = (const float*)d_in[4];
  const float* a2  = (const float*)d_in[5];
  const float* W3  = (const float*)d_in[6];
  const float* a3  = (const float*)d_in[7];
  const float* Wg0 = (const float*)d_in[8];
  const float* bg0 = (const float*)d_in[9];
  const float* Wg1 = (const float*)d_in[10];
  const float* bg1 = (const float*)d_in[11];
  const float* Wr  = (const float*)d_in[12];
  const float* br  = (const float*)d_in[13];
  const int*   rel = (const int*)d_in[14];
  float* out = (float*)d_out;

  char* ws = (char*)d_ws;
  float* Wh    = (float*)(ws + 0);         // 3*N*64 f32 = 3 MB
  float* h     = (float*)(ws + 3145728);   // 3*N*64
  float* ssrc  = (float*)(ws + 6291456);   // 3*N
  float* sdst  = (float*)(ws + 6340608);   // 3*N
  int*   nbr   = (int*)  (ws + 6389760);   // N*128 int
  int*   nbrc  = (int*)  (ws + 8486912);   // N int
  float* dinv  = (float*)(ws + 8503296);   // N
  float* sup0  = (float*)(ws + 8519680);   // N*64
  float* s1    = (float*)(ws + 9568256);   // N*32
  float* resid = (float*)(ws + 10092544);  // N*32  (ends 10616832 bytes)

  k_wh<<<dim3(N / 64, 3), 256, 0, stream>>>(x, W1, W2, W3, a1, a2, a3, Wh, ssrc, sdst);
  k_attn<<<dim3(N / 4, 3), 256, 0, stream>>>(adj, Wh, ssrc, sdst, rel, h, nbr, nbrc, dinv);
  k_support0<<<N / 64, 256, 0, stream>>>(h, Wg0, sup0);
  k_agg0_gemm1<<<N / 4, 256, 0, stream>>>(sup0, nbr, nbrc, dinv, bg0, Wg1, Wr, br, s1, resid);
  k_agg1<<<N / 8, 256, 0, stream>>>(s1, resid, nbr, nbrc, dinv, bg1, out);
}

// Round 10
// 402.193 us; speedup vs baseline: 1.4943x; 1.0096x over previous
//
#include <hip/hip_runtime.h>

#define N 4096
#define IN_F 256
#define SLOPE 0.01f
#define CAP 256      // neighbor capacity/row (mean ~41, sigma ~6.4 -> 33 sigma)
#define NBR_CAP 128  // persisted neighbor list capacity (worst row ~80)

typedef float f4 __attribute__((ext_vector_type(4)));

__device__ __forceinline__ float leaky(float v) { return v >= 0.f ? v : SLOPE * v; }

// ---------------------------------------------------------------------------
// Wh[r] = x @ W_r  (x: [N,256], W: [256,64]) + fused s_src/s_dst epilogue.
// grid (N/64, 3), block 256
// ---------------------------------------------------------------------------
__global__ __launch_bounds__(256) void k_wh(const float* __restrict__ x,
                                            const float* __restrict__ W1,
                                            const float* __restrict__ W2,
                                            const float* __restrict__ W3,
                                            const float* __restrict__ a1,
                                            const float* __restrict__ a2,
                                            const float* __restrict__ a3,
                                            float* __restrict__ Wh,
                                            float* __restrict__ ssrc,
                                            float* __restrict__ sdst) {
  const int r = blockIdx.y;
  const float* W = (r == 0) ? W1 : (r == 1 ? W2 : W3);
  const float* aW = (r == 0) ? a1 : (r == 1 ? a2 : a3);
  const int row0 = blockIdx.x * 64;
  __shared__ float xs[64][32];
  __shared__ float wsh[32][64];
  const int tid = threadIdx.x;
  const int f = tid & 63;
  const int rg = tid >> 6;  // 0..3
  float acc[16];
#pragma unroll
  for (int t = 0; t < 16; ++t) acc[t] = 0.f;

  for (int kb = 0; kb < IN_F; kb += 32) {
#pragma unroll
    for (int t = 0; t < 8; ++t) {  // 64x32 x-tile
      int idx = tid + t * 256;
      int rr = idx >> 5, cc = idx & 31;
      xs[rr][cc] = x[(size_t)(row0 + rr) * IN_F + kb + cc];
    }
#pragma unroll
    for (int t = 0; t < 8; ++t) {  // 32x64 W-tile
      int idx = tid + t * 256;
      int rr = idx >> 6, cc = idx & 63;
      wsh[rr][cc] = W[(size_t)(kb + rr) * 64 + cc];
    }
    __syncthreads();
#pragma unroll
    for (int kk = 0; kk < 32; ++kk) {
      float wv = wsh[kk][f];
#pragma unroll
      for (int t = 0; t < 16; ++t) acc[t] += xs[rg * 16 + t][kk] * wv;
    }
    __syncthreads();
  }
  float* outp = Wh + ((size_t)r * N + row0 + rg * 16) * 64 + f;
#pragma unroll
  for (int t = 0; t < 16; ++t) outp[(size_t)t * 64] = acc[t];

  // fused scores epilogue: s_src = Wh·a[:64], s_dst = Wh·a[64:]
  const float asrc = aW[f];
  const float adst = aW[64 + f];
#pragma unroll
  for (int t = 0; t < 16; ++t) {
    float p = acc[t] * asrc;
    float q = acc[t] * adst;
#pragma unroll
    for (int off = 32; off; off >>= 1) {
      p += __shfl_down(p, off);
      q += __shfl_down(q, off);
    }
    if (f == 0) {
      const int row = row0 + rg * 16 + t;
      ssrc[r * N + row] = p;
      sdst[r * N + row] = q;
    }
  }
}

// ---------------------------------------------------------------------------
// Wave-per-row fused attention, chunked double-buffered scan (no reg spill):
// 2 groups of 4 f4 regs; issue next group's loads before processing current.
// Ballot-compact nz indices -> exact softmax -> PV. No atomics/syncthreads.
// grid (N/4, 3), block 256 (4 waves = 4 rows per block).
// ---------------------------------------------------------------------------
__global__ __launch_bounds__(256, 4) void k_attn(const float* __restrict__ adj,
                                                 const float* __restrict__ Wh,
                                                 const float* __restrict__ ssrc,
                                                 const float* __restrict__ sdst,
                                                 const int* __restrict__ relp,
                                                 float* __restrict__ hout,
                                                 int* __restrict__ nbr,
                                                 int* __restrict__ nbrc,
                                                 float* __restrict__ dinv) {
  const int r = blockIdx.y;
  const int wave = threadIdx.x >> 6;
  const int lane = threadIdx.x & 63;
  const int i = blockIdx.x * 4 + wave;

  __shared__ int s_idx_all[4][CAP];
  __shared__ float s_p_all[4][CAP];
  int* s_idx = s_idx_all[wave];
  float* s_p = s_p_all[wave];

  const f4* arow4 = (const f4*)(adj + ((size_t)r * N + i) * N);
  const float* sd = sdst + r * N;
  const unsigned long long lmask = (1ULL << lane) - 1ULL;
  int base = 0;

  auto proc4 = [&](const f4& v, int tAbs) {
#pragma unroll
    for (int c = 0; c < 4; ++c) {
      const bool nz = (v[c] != 0.f);
      const unsigned long long m = __ballot(nz);
      if (nz) {
        const int pos = base + __popcll(m & lmask);
        if (pos < CAP) s_idx[pos] = (tAbs * 64 + lane) * 4 + c;
      }
      base += __popcll(m);
    }
  };

  f4 A0, A1, A2, A3, B0, B1, B2, B3;
  A0 = arow4[0 * 64 + lane];  A1 = arow4[1 * 64 + lane];
  A2 = arow4[2 * 64 + lane];  A3 = arow4[3 * 64 + lane];

  B0 = arow4[4 * 64 + lane];  B1 = arow4[5 * 64 + lane];
  B2 = arow4[6 * 64 + lane];  B3 = arow4[7 * 64 + lane];
  proc4(A0, 0);  proc4(A1, 1);  proc4(A2, 2);  proc4(A3, 3);

  A0 = arow4[8 * 64 + lane];  A1 = arow4[9 * 64 + lane];
  A2 = arow4[10 * 64 + lane]; A3 = arow4[11 * 64 + lane];
  proc4(B0, 4);  proc4(B1, 5);  proc4(B2, 6);  proc4(B3, 7);

  B0 = arow4[12 * 64 + lane]; B1 = arow4[13 * 64 + lane];
  B2 = arow4[14 * 64 + lane]; B3 = arow4[15 * 64 + lane];
  proc4(A0, 8);  proc4(A1, 9);  proc4(A2, 10); proc4(A3, 11);

  proc4(B0, 12); proc4(B1, 13); proc4(B2, 14); proc4(B3, 15);

  const int Ktrue = base;
  const int K = (Ktrue < CAP) ? Ktrue : CAP;

  // --- exact row max: M = leaky(si + max_nbr sd) (leaky monotone) ---
  const float si = ssrc[r * N + i];
  float sdv = 0.f;
  float mx = -1e30f;
  if (lane < K) {
    sdv = sd[s_idx[lane]];
    mx = sdv;
  }
  for (int k = 64 + lane; k < K; k += 64) mx = fmaxf(mx, sd[s_idx[k]]);  // rare tail
#pragma unroll
  for (int off = 1; off < 64; off <<= 1) mx = fmaxf(mx, __shfl_xor(mx, off));
  const float M = leaky(si + mx);

  // --- p_k = exp(score - M); denom via butterfly (all lanes get it) ---
  float lsum = 0.f;
  if (lane < K) {
    const float p = __expf(leaky(si + sdv) - M);
    s_p[lane] = p;
    lsum = p;
  }
  for (int k = 64 + lane; k < K; k += 64) {  // rare tail
    const float p = __expf(leaky(si + sd[s_idx[k]]) - M);
    s_p[k] = p;
    lsum += p;
  }
#pragma unroll
  for (int off = 1; off < 64; off <<= 1) lsum += __shfl_xor(lsum, off);
  const float inv = 1.f / lsum;

  // --- PV: h[i][lane] = sum_k p_k * Wh[j_k][lane], 4-way unrolled MLP ---
  const float* WhR = Wh + (size_t)r * N * 64;
  float acc = 0.f;
  int k = 0;
  for (; k + 4 <= K; k += 4) {
    const int i0 = s_idx[k], i1 = s_idx[k + 1], i2 = s_idx[k + 2], i3 = s_idx[k + 3];
    const float w0 = s_p[k], w1 = s_p[k + 1], w2 = s_p[k + 2], w3 = s_p[k + 3];
    acc += w0 * WhR[(size_t)i0 * 64 + lane];
    acc += w1 * WhR[(size_t)i1 * 64 + lane];
    acc += w2 * WhR[(size_t)i2 * 64 + lane];
    acc += w3 * WhR[(size_t)i3 * 64 + lane];
  }
  for (; k < K; ++k) acc += s_p[k] * WhR[(size_t)s_idx[k] * 64 + lane];
  hout[((size_t)r * N + i) * 64 + lane] = acc * inv;

  // --- persist sparse structure for the GNN relation ---
  if (r == relp[0]) {
    const int Kp = (K < NBR_CAP) ? K : NBR_CAP;
    if (lane == 0) {
      nbrc[i] = Kp;
      dinv[i] = 1.f / (float)Ktrue;  // deg = nnz count (0/1 values)
    }
    for (int kk = lane; kk < Kp; kk += 64) nbr[i * NBR_CAP + kk] = s_idx[kk];
  }
}

// ---------------------------------------------------------------------------
// hp = sigmoid((h1+h2+h3)/3); support0 = hp @ Wg0 ([64,64])
// grid N/64, block 256
// ---------------------------------------------------------------------------
__global__ __launch_bounds__(256) void k_support0(const float* __restrict__ h,
                                                  const float* __restrict__ Wg0,
                                                  float* __restrict__ sup0) {
  __shared__ float hp[64][64];
  __shared__ float wg[64][64];
  const int tid = threadIdx.x;
  const int row0 = blockIdx.x * 64;
  const float* h1 = h;
  const float* h2 = h + (size_t)N * 64;
  const float* h3 = h + (size_t)2 * N * 64;
#pragma unroll
  for (int t = 0; t < 16; ++t) {
    int idx = tid + t * 256;
    wg[idx >> 6][idx & 63] = Wg0[idx];
    size_t gi = (size_t)row0 * 64 + idx;
    float v = (h1[gi] + h2[gi] + h3[gi]) * (1.f / 3.f);
    hp[idx >> 6][idx & 63] = 1.f / (1.f + __expf(-v));
  }
  __syncthreads();
  const int f = tid & 63;
  const int g = tid >> 6;
  for (int n = g; n < 64; n += 4) {
    float acc = 0.f;
#pragma unroll
    for (int k = 0; k < 64; ++k) acc += hp[n][k] * wg[k][f];
    sup0[((size_t)row0 + n) * 64 + f] = acc;
  }
}

// ---------------------------------------------------------------------------
// Fused GNN layer 0 epilogue + layer-1 GEMMs, 4 rows per block:
//   out0[i]  = leaky(dinv[i] * sum_{j in nbr(i)} sup0[j] + bg0)   (kept in LDS)
//   s1[i]    = out0[i] @ Wg1            (Wg1: [64,32])
//   resid[i] = out0[i] @ Wr^T + br      (Wr: [32,64] torch layout)
// grid N/4, block 256
// ---------------------------------------------------------------------------
__global__ __launch_bounds__(256) void k_agg0_gemm1(const float* __restrict__ sup,
                                                    const int* __restrict__ nbr,
                                                    const int* __restrict__ nbrc,
                                                    const float* __restrict__ dinv,
                                                    const float* __restrict__ bg0,
                                                    const float* __restrict__ Wg1,
                                                    const float* __restrict__ Wr,
                                                    const float* __restrict__ br,
                                                    float* __restrict__ s1,
                                                    float* __restrict__ resid) {
  __shared__ float wg[64][32];
  __shared__ float wrT[64][33];  // padded; wrT[k][ff] = Wr[ff][k]
  __shared__ float row_s[4][64];
  const int tid = threadIdx.x;
#pragma unroll
  for (int t = 0; t < 8; ++t) {
    int idx = tid + t * 256;
    wg[idx >> 5][idx & 31] = Wg1[idx];
    wrT[idx & 63][idx >> 6] = Wr[idx];
  }
  const int f = tid & 63;
  const int g = tid >> 6;
  const int i = blockIdx.x * 4 + g;

  // --- agg0: out0 row into LDS ---
  const int K = nbrc[i];
  const int* nb = nbr + (size_t)i * NBR_CAP;
  float acc = 0.f;
  for (int k = 0; k < K; ++k) acc += sup[(size_t)nb[k] * 64 + f];
  row_s[g][f] = leaky(acc * dinv[i] + bg0[f]);
  __syncthreads();

  // --- layer-1 GEMMs from LDS ---
  const float* row = row_s[g];
  if (f < 32) {
    float a2 = 0.f;
#pragma unroll
    for (int k = 0; k < 64; ++k) a2 += row[k] * wg[k][f];
    s1[(size_t)i * 32 + f] = a2;
  } else {
    const int ff = f - 32;
    float a2 = br[ff];
#pragma unroll
    for (int k = 0; k < 64; ++k) a2 += row[k] * wrT[k][ff];
    resid[(size_t)i * 32 + ff] = a2;
  }
}

// ---------------------------------------------------------------------------
// out[i] = leaky(dinv[i] * sum_j s1[j] + bg1) + resid[i]   grid N/8, block 256
// ---------------------------------------------------------------------------
__global__ __launch_bounds__(256) void k_agg1(const float* __restrict__ s1,
                                              const float* __restrict__ resid,
                                              const int* __restrict__ nbr,
                                              const int* __restrict__ nbrc,
                                              const float* __restrict__ dinv,
                                              const float* __restrict__ bias,
                                              float* __restrict__ out) {
  const int tid = threadIdx.x;
  const int f = tid & 31;
  const int g = tid >> 5;
  const int i = blockIdx.x * 8 + g;
  const int K = nbrc[i];
  const int* nb = nbr + (size_t)i * NBR_CAP;
  float acc = 0.f;
  for (int k = 0; k < K; ++k) acc += s1[(size_t)nb[k] * 32 + f];
  out[(size_t)i * 32 + f] = leaky(acc * dinv[i] + bias[f]) + resid[(size_t)i * 32 + f];
}

// ---------------------------------------------------------------------------
extern "C" void kernel_launch(void* const* d_in, const int* in_sizes, int n_in,
                              void* d_out, int out_size, void* d_ws, size_t ws_size,
                              hipStream_t stream) {
  const float* x   = (const float*)d_in[0];
  const float* adj = (const float*)d_in[1];
  const float* W1  = (const float*)d_in[2];
  const float* a1  = (const float*)d_in[3];
  const float* W2  = (const float*)d_in[4];
  const float* a2  = (const float*)d_in[5];
  const float* W3  = (const float*)d_in[6];
  const float* a3  = (const float*)d_in[7];
  const float* Wg0 = (const float*)d_in[8];
  const float* bg0 = (const float*)d_in[9];
  const float* Wg1 = (const float*)d_in[10];
  const float* bg1 = (const float*)d_in[11];
  const float* Wr  = (const float*)d_in[12];
  const float* br  = (const float*)d_in[13];
  const int*   rel = (const int*)d_in[14];
  float* out = (float*)d_out;

  char* ws = (char*)d_ws;
  float* Wh    = (float*)(ws + 0);         // 3*N*64 f32 = 3 MB
  float* h     = (float*)(ws + 3145728);   // 3*N*64
  float* ssrc  = (float*)(ws + 6291456);   // 3*N
  float* sdst  = (float*)(ws + 6340608);   // 3*N
  int*   nbr   = (int*)  (ws + 6389760);   // N*128 int
  int*   nbrc  = (int*)  (ws + 8486912);   // N int
  float* dinv  = (float*)(ws + 8503296);   // N
  float* sup0  = (float*)(ws + 8519680);   // N*64
  float* s1    = (float*)(ws + 9568256);   // N*32
  float* resid = (float*)(ws + 10092544);  // N*32  (ends 10616832 bytes)

  k_wh<<<dim3(N / 64, 3), 256, 0, stream>>>(x, W1, W2, W3, a1, a2, a3, Wh, ssrc, sdst);
  k_attn<<<dim3(N / 4, 3), 256, 0, stream>>>(adj, Wh, ssrc, sdst, rel, h, nbr, nbrc, dinv);
  k_support0<<<N / 64, 256, 0, stream>>>(h, Wg0, sup0);
  k_agg0_gemm1<<<N / 4, 256, 0, stream>>>(sup0, nbr, nbrc, dinv, bg0, Wg1, Wr, br, s1, resid);
  k_agg1<<<N / 8, 256, 0, stream>>>(s1, resid, nbr, nbrc, dinv, bg1, out);
}